// Round 9
// baseline (160.090 us; speedup 1.0000x reference)
//
#include <hip/hip_runtime.h>

#define BB  8
#define CC  64
#define HH  128
#define WW  128
#define OCC 18   // 2*KK offset channels
#define XP  133  // padded spatial dim (pad 2 low, 3 high; offsets clipped to +-1)
#define SP  72   // LDS pitch in shorts (144B: 16B-aligned, measured 0 conflicts)
#define XTP 68   // transpose-LDS pitch

typedef __attribute__((ext_vector_type(8)))  short bf16x8;
typedef __attribute__((ext_vector_type(16))) float f32x16;
typedef __attribute__((ext_vector_type(2)))  float v2f;

static __device__ __forceinline__ ushort f2bf(float f) {
    union { float f; unsigned u; } v; v.f = f;
    unsigned r = (v.u + 0x7FFFu + ((v.u >> 16) & 1u)) >> 16;  // RNE
    return (ushort)r;
}
static __device__ __forceinline__ float bfu(unsigned u) {
    union { unsigned u; float f; } v; v.u = u; return v.f;
}
static __device__ __forceinline__ unsigned uf(float f) {
    union { float f; unsigned u; } v; v.f = f; return v.u;
}

// ---------------------------------------------------------------------------
// PREP (single launch): blocks 0..2047 build XT with batch-per-XCD placement
// (b = blockIdx&7 so XT[b] is written by—and stays resident in—XCD b's L2);
// blocks 2048..2247 build WAf; 2248..2391 build WDf. (unchanged from r8)
// ---------------------------------------------------------------------------
__global__ __launch_bounds__(256) void prep_kernel(
    const float* __restrict__ x, const float* __restrict__ w,
    const float* __restrict__ ow, ushort* __restrict__ XT,
    ushort* __restrict__ WAf, ushort* __restrict__ WDf)
{
    __shared__ ushort T[64 * XTP];
    const int tid = threadIdx.x;
    const int phys = blockIdx.x;

    if (phys >= 2 * BB * HH) {                    // weight-prep blocks
        int id = phys - 2 * BB * HH;
        if (id < 200) {                           // WAf: 51200 elements
            int idx = id * 256 + tid;
            int j  = idx & 7;
            int l  = (idx >> 3) & 63;
            int cs = (idx >> 9) & 3;
            int t  = idx >> 11;
            int oc = l & 31;
            int c  = cs * 16 + (l >> 5) * 8 + j;
            float v = (oc < OCC) ? ow[((size_t)(oc * CC + c)) * 25 + t] : 0.f;
            WAf[idx] = f2bf(v);
        } else {                                  // WDf: 36864 elements
            int idx = (id - 200) * 256 + tid;
            int j  = idx & 7;
            int l  = (idx >> 3) & 63;
            int cs = (idx >> 9) & 3;
            int mt = (idx >> 11) & 1;
            int t  = idx >> 12;
            int o  = mt * 32 + (l & 31);
            int c  = cs * 16 + (l >> 5) * 8 + j;
            WDf[idx] = f2bf(w[((size_t)(o * CC + c)) * 9 + t]);
        }
        return;
    }

    const int b    = phys & 7;                    // XCD id == batch
    const int idx  = phys >> 3;
    const int half = idx & 1;
    const int y    = idx >> 1;

    {   // y-border zero rows {0,1,130,131,132}
        int j = idx * 256 + tid;
        if (j < 5 * XP * 8) {
            int r   = j / (XP * 8);
            int off = j % (XP * 8);
            int yp  = (r < 2) ? r : (128 + r);
            ((uint4*)(XT + ((size_t)b * XP + yp) * XP * 64))[off] = make_uint4(0, 0, 0, 0);
        }
    }

    const int p   = tid & 63;
    const int ch4 = tid >> 6;
    const float* xb = x + (size_t)b * CC * HH * WW + (size_t)y * WW + half * 64;
#pragma unroll
    for (int i = 0; i < 16; i++) {
        int c = i * 4 + ch4;
        T[p * XTP + c] = f2bf(xb[(size_t)c * HH * WW + p]);
    }
    __syncthreads();

    ushort* orow = XT + (((size_t)b * XP + (y + 2)) * XP) * 64;

    if (half == 0) {
        if (tid < 16) {
            int col = tid >> 3;
            ((uint4*)(orow + (size_t)col * 64))[tid & 7] = make_uint4(0, 0, 0, 0);
        }
    } else {
        if (tid < 24) {
            int col = 130 + (tid >> 3);
            ((uint4*)(orow + (size_t)col * 64))[tid & 7] = make_uint4(0, 0, 0, 0);
        }
    }

#pragma unroll
    for (int g = 0; g < 2; g++) {
        int i2 = g * 256 + tid;
        int pl = i2 >> 3;
        int part = i2 & 7;
        uint2 lo = *(const uint2*)&T[pl * XTP + part * 8];
        uint2 hi = *(const uint2*)&T[pl * XTP + part * 8 + 4];
        uint4 wv; wv.x = lo.x; wv.y = lo.y; wv.z = hi.x; wv.w = hi.y;
        ((uint4*)(orow + ((size_t)(half * 64 + pl + 2)) * 64))[part] = wv;
    }
}

// ---------------------------------------------------------------------------
// Gather context for one deform tap: 8 corner uint4s + bilinear weights
// ---------------------------------------------------------------------------
struct TapCtx { uint4 q[8]; float w00, w01, w10, w11; };

static __device__ __forceinline__ void tap_load(
    const ushort* __restrict__ xtb, const float* __restrict__ off_lds,
    int y, int half, int p, int cs4, int t, TapCtx& c)
{
    float dy = off_lds[(2 * t) * 64 + p];
    float dx = off_lds[(2 * t + 1) * 64 + p];
    float py = (float)(y + t / 3 - 1) + dy;
    float px = (float)(half * 64 + p + t % 3 - 1) + dx;
    float y0f = floorf(py), x0f = floorf(px);
    float fy = py - y0f, fx = px - x0f;
    int iy = (int)y0f + 2, ix = (int)x0f + 2;
    c.w00 = (1.f - fy) * (1.f - fx); c.w01 = (1.f - fy) * fx;
    c.w10 = fy * (1.f - fx);         c.w11 = fy * fx;
    const ushort* c00 = xtb + ((size_t)iy * XP + ix) * 64 + cs4;
    const ushort* c10 = c00 + XP * 64;
    c.q[0] = *(const uint4*)(c00);      c.q[1] = *(const uint4*)(c00 + 8);
    c.q[2] = *(const uint4*)(c00 + 64); c.q[3] = *(const uint4*)(c00 + 72);
    c.q[4] = *(const uint4*)(c10);      c.q[5] = *(const uint4*)(c10 + 8);
    c.q[6] = *(const uint4*)(c10 + 64); c.q[7] = *(const uint4*)(c10 + 72);
}

// ---------------------------------------------------------------------------
// FUSED kernel, round 9: double-buffered XROW/S (1 barrier per ky / per tap),
// software-pipelined gather (tap t+1 issued before tap t's MFMA), packed-f32
// bilinear blend + cheap round-half-up bf16 pack.
// ---------------------------------------------------------------------------
__global__ __launch_bounds__(256, 4) void fused_kernel(
    const ushort* __restrict__ XT, const ushort* __restrict__ WAf,
    const ushort* __restrict__ WDf, const float* __restrict__ ob,
    float* __restrict__ out)
{
    __shared__ __align__(16) char smem0[68 * SP * 2];   // 9792 B (XROW0 / red / S0)
    __shared__ __align__(16) char smem1[68 * SP * 2];   // 9792 B (XROW1 / S1)
    __shared__ float off_lds[OCC * 64];                 // 4608 B

    const int tid   = threadIdx.x;
    const int lane  = tid & 63;
    const int n     = lane & 31;
    const int h     = lane >> 5;
    const int w     = tid >> 6;
    const int ptile = w & 1;          // 32-wide px tile (A) / o tile (B)
    const int tset  = w >> 1;         // cs-half (A) / px tile (B)

    // batch-per-XCD swizzle (same mapping as prep => XT[b] L2-resident)
    const int b    = blockIdx.x & 7;
    const int idx  = blockIdx.x >> 3;
    const int half = idx & 1;
    const int y    = idx >> 1;

    // ================= Phase A: offset conv row-half ======================
    {
        ushort* XR[2] = { (ushort*)smem0, (ushort*)smem1 };
        float*  red   = (float*)smem0;
        f32x16 acc = {};
        const uint4* srcb = (const uint4*)(XT + (((size_t)b * XP + y) * XP + half * 64) * 64);

        // stage ky=0 into XR[0]
#pragma unroll
        for (int k = 0; k < 3; k++) {
            int i = tid + k * 256;
            if (i < 544) {
                uint4 v = srcb[i];
                *(uint4*)&XR[0][(i >> 3) * SP + (i & 7) * 8] = v;
            }
        }
        __syncthreads();

#pragma unroll
        for (int ky = 0; ky < 5; ky++) {
            ushort* Xc = XR[ky & 1];

            // issue next row's global loads (consumed after compute)
            uint4 pf[3];
            if (ky < 4) {
                const uint4* src = srcb + (size_t)(ky + 1) * XP * 8;
#pragma unroll
                for (int k = 0; k < 3; k++) {
                    int i = tid + k * 256;
                    if (i < 544) pf[k] = src[i];
                }
            }

#pragma unroll
            for (int kx = 0; kx < 5; kx++) {
                const int t = ky * 5 + kx;
                const ushort* bbase = &Xc[(ptile * 32 + n + kx) * SP + h * 8];
#pragma unroll
                for (int c2 = 0; c2 < 2; c2++) {
                    const int cs = tset * 2 + c2;
                    bf16x8 af = *(const bf16x8*)(WAf + (((size_t)t * 4 + cs) * 64 + lane) * 8);
                    bf16x8 bf = *(const bf16x8*)(bbase + cs * 16);
                    acc = __builtin_amdgcn_mfma_f32_32x32x16_bf16(af, bf, acc, 0, 0, 0);
                }
            }

            if (ky < 4) {
                ushort* Xn = XR[(ky + 1) & 1];
#pragma unroll
                for (int k = 0; k < 3; k++) {
                    int i = tid + k * 256;
                    if (i < 544) *(uint4*)&Xn[(i >> 3) * SP + (i & 7) * 8] = pf[k];
                }
            }
            __syncthreads();
        }

        if (tset == 1) {
#pragma unroll
            for (int r = 0; r < 16; r++)
                red[ptile * 1024 + r * 64 + lane] = acc[r];
        }
        __syncthreads();
        if (tset == 0) {
#pragma unroll
            for (int r = 0; r < 16; r++) {
                int oc = (r & 3) + 8 * (r >> 2) + 4 * h;
                if (oc < OCC) {
                    float v = acc[r] + red[ptile * 1024 + r * 64 + lane] + ob[oc];
                    v = fminf(fmaxf(v, -1.f), 1.f);
                    off_lds[oc * 64 + ptile * 32 + n] = v;
                }
            }
        }
        __syncthreads();   // off_lds ready; red reads done (S0 reuse safe)
    }

    // ================= Phase B: deform sample + einsum ====================
    ushort* Sb[2] = { (ushort*)smem0, (ushort*)smem1 };
    const int p   = tid >> 2;                     // gather pixel (4 lanes/pixel)
    const int cs4 = (tid & 3) * 16;               // channel section (shorts)
    const int m0  = ptile * 32;                   // o tile
    const int n0  = tset * 32;                    // px tile

    f32x16 acc = {};
    const ushort* xtb = XT + (size_t)b * XP * XP * 64;

    TapCtx cur, nxt;
    tap_load(xtb, off_lds, y, half, p, cs4, 0, cur);

#pragma unroll
    for (int t = 0; t < 9; t++) {
        ushort* St = Sb[t & 1];

        // repack current tap: packed-f32 blend, round-half-up bf16 pack
#pragma unroll
        for (int m = 0; m < 2; m++) {
            unsigned o4[4];
#pragma unroll
            for (int j = 0; j < 4; j++) {
                unsigned u00 = ((const unsigned*)&cur.q[m])[j];
                unsigned u01 = ((const unsigned*)&cur.q[2 + m])[j];
                unsigned u10 = ((const unsigned*)&cur.q[4 + m])[j];
                unsigned u11 = ((const unsigned*)&cur.q[6 + m])[j];
                v2f a  = { bfu(u00 << 16), bfu(u00 & 0xffff0000u) };
                v2f bb = { bfu(u01 << 16), bfu(u01 & 0xffff0000u) };
                v2f cc = { bfu(u10 << 16), bfu(u10 & 0xffff0000u) };
                v2f dd = { bfu(u11 << 16), bfu(u11 & 0xffff0000u) };
                v2f r = a * cur.w00 + bb * cur.w01 + cc * cur.w10 + dd * cur.w11;
                unsigned rl = uf(r.x) + 0x8000u;
                unsigned rh = uf(r.y) + 0x8000u;
                o4[j] = (rl >> 16) | (rh & 0xffff0000u);
            }
            *(uint4*)&St[p * SP + cs4 + m * 8] = *(uint4*)o4;
        }

        // pipeline: issue next tap's gather before the barrier
        if (t < 8) tap_load(xtb, off_lds, y, half, p, cs4, t + 1, nxt);

        __syncthreads();

        const ushort* bp = &St[(n0 + n) * SP + h * 8];
#pragma unroll
        for (int cs = 0; cs < 4; cs++) {
            bf16x8 af = *(const bf16x8*)(WDf + ((((size_t)t * 2 + ptile) * 4 + cs) * 64 + lane) * 8);
            bf16x8 bf = *(const bf16x8*)(bp + cs * 16);
            acc = __builtin_amdgcn_mfma_f32_32x32x16_bf16(af, bf, acc, 0, 0, 0);
        }
        cur = nxt;   // fully unrolled -> register-renamed, no copies
    }

    // epilogue: C/D col=lane&31 (px), row=(r&3)+8*(r>>2)+4*h (o)
#pragma unroll
    for (int r = 0; r < 16; r++) {
        int o = m0 + (r & 3) + 8 * (r >> 2) + 4 * h;
        out[((size_t)(b * CC + o) * HH + y) * WW + half * 64 + n0 + n] = acc[r];
    }
}

// ---------------------------------------------------------------------------
extern "C" void kernel_launch(void* const* d_in, const int* in_sizes, int n_in,
                              void* d_out, int out_size, void* d_ws, size_t ws_size,
                              hipStream_t stream)
{
    const float* x  = (const float*)d_in[0];   // (8,64,128,128)
    const float* w  = (const float*)d_in[1];   // (64,64,3,3)
    const float* ow = (const float*)d_in[2];   // (18,64,5,5)
    const float* ob = (const float*)d_in[3];   // (18,)
    float* out = (float*)d_out;                // (8,64,128,128)

    // workspace: XT 18,113,536 | WAf 102,400 | WDf 73,728
    ushort* XT  = (ushort*)d_ws;
    ushort* WAf = (ushort*)((char*)d_ws + 18113536);
    ushort* WDf = (ushort*)((char*)d_ws + 18215936);

    prep_kernel<<<2 * BB * HH + 344, 256, 0, stream>>>(x, w, ow, XT, WAf, WDf);
    fused_kernel<<<2 * BB * HH, 256, 0, stream>>>(XT, WAf, WDf, ob, out);
}